// Round 3
// baseline (194.066 us; speedup 1.0000x reference)
//
#include <hip/hip_runtime.h>
#include <math.h>

#define MIN_T    0.01f
#define MAX_T    0.5f
#define LESION_T 0.3f

constexpr int NB       = 16;
constexpr int DIM      = 128;
constexpr int PLANE_F4 = DIM * DIM / 4;        // 4096 float4 per plane
constexpr int VOX      = DIM * DIM * DIM;      // 2,097,152
constexpr int THREADS  = 512;                  // 16 rows x 32 float4-cols
constexpr int ROWS     = 16;                   // rows of a plane per block
constexpr int HWBLKS   = DIM / ROWS;           // 8 row-slabs
constexpr int DSEGS    = 8;                    // d-axis segments (4->8: occupancy)
constexpr int DPS      = DIM / DSEGS;          // 16 planes per segment
constexpr int NACC     = 8;
constexpr int SLOTS_PER_B = DSEGS * HWBLKS;    // 64 partial slots per batch
constexpr int NWAVES   = THREADS / 64;         // 8

// Per-slot accumulator layout (floats):
// 0: cnt(>MIN_T)  1: cnt(>MAX_T)  2: sum|d-diff|  3: sum|h-diff|
// 4: sum|w-diff|  5: sum s*mask   6: sum s^2*mask 7: cnt(>LESION_T)
//
// Structure notes (evidence, rounds 0-2):
//  - dual-load of row h+1 (vh) is an L1 hit for 15/16 rows; LDS plane-exchange
//    with per-plane barriers measured ~3-4us SLOWER. Keep dual-load.
//  - direct per-slot stores: no memset dispatch, no atomics. (absmax 0)
//  - R3: grid 1024 blocks = 4 blocks/CU = 32 waves/CU (max). launch_bounds
//    (512,8) forces VGPR<=64. Ballot counting moves 3 counters to SGPRs
//    (frees VGPRs, cuts ~24 VALU/iter onto the parallel scalar pipe).
__global__ __launch_bounds__(THREADS, 8)
void partial_kernel(const float* __restrict__ pred, float* __restrict__ ws)
{
    const int seg   = blockIdx.x;
    const int hwblk = blockIdx.y;
    const int b     = blockIdx.z;
    const int tid   = (int)threadIdx.x;
    const int r     = tid >> 5;                // local row 0..15

    const int  h    = hwblk * ROWS + r;
    const bool do_h = (h < DIM - 1);           // h-pair (h,h+1) exists
    const bool do_w = ((tid & 31) != 31);      // w-cross pair exists

    const float4* __restrict__ s4 =
        reinterpret_cast<const float4*>(pred + (size_t)b * VOX);

    const int d0    = seg * DPS;
    const int d_end = (seg == DSEGS - 1) ? (DIM - 1) : (d0 + DPS);

    // wave-uniform integer counters (SGPR) via ballot/popcount
    unsigned int wmin = 0, wmax = 0, wles = 0;
    float sum_d = 0.f, sum_h = 0.f, sum_w = 0.f, sm = 0.f, sm2 = 0.f;
    const float4 zero4 = { 0.f, 0.f, 0.f, 0.f };

    // element stats + w/h diffs for one float4 (its plane)
    auto process = [&](const float4& v, const float4& vh) {
        const float xs[4] = { v.x, v.y, v.z, v.w };
        #pragma unroll
        for (int j = 0; j < 4; ++j) {
            const float x = xs[j];
            wmin += (unsigned)__popcll(__ballot(x > MIN_T));
            wmax += (unsigned)__popcll(__ballot(x > MAX_T));
            wles += (unsigned)__popcll(__ballot(x > LESION_T));
            const float y = (x > MIN_T) ? x : 0.0f;   // cmp shared with ballot
            sm  += y;
            sm2  = fmaf(x, y, sm2);
        }
        sum_w += fabsf(v.y - v.x) + fabsf(v.z - v.y) + fabsf(v.w - v.z);
        const float nx = __shfl_down(v.x, 1, 64);   // next float4's .x (same row)
        if (do_w) sum_w += fabsf(nx - v.w);
        if (do_h) sum_h += fabsf(vh.x - v.x) + fabsf(vh.y - v.y)
                         + fabsf(vh.z - v.z) + fabsf(vh.w - v.w);
    };

    // thread owns float4 at (h, w4 = tid&31) on every plane
    size_t base = (size_t)d0 * PLANE_F4 + hwblk * THREADS + tid;

    float4 v  = s4[base];
    float4 vh = do_h ? s4[base + 32] : zero4;   // row h+1 (L1 hit for r<15)

    // pairs (d-1, d) for d in [d0+1, d_end]; stats for planes d0 .. d_end-1
    for (int d = d0 + 1; d <= d_end; ++d) {
        base += PLANE_F4;
        const float4 nv  = s4[base];                       // prefetch next plane
        const float4 nvh = do_h ? s4[base + 32] : zero4;
        process(v, vh);
        sum_d += fabsf(nv.x - v.x) + fabsf(nv.y - v.y)
               + fabsf(nv.z - v.z) + fabsf(nv.w - v.w);
        v = nv; vh = nvh;
    }
    if (seg == DSEGS - 1)       // plane 127's element stats (not a d-pair source)
        process(v, vh);

    // wave (64-lane) shuffle reduction for the 5 float sums;
    // wmin/wmax/wles are already wave-reduced (uniform).
    float fvals[5] = { sum_d, sum_h, sum_w, sm, sm2 };
    #pragma unroll
    for (int vi = 0; vi < 5; ++vi) {
        float x = fvals[vi];
        #pragma unroll
        for (int off = 32; off > 0; off >>= 1)
            x += __shfl_down(x, off, 64);
        fvals[vi] = x;
    }

    __shared__ float red[NWAVES][NACC];
    const int wave = tid >> 6;
    const int lane = tid & 63;
    if (lane == 0) {
        red[wave][0] = (float)wmin;
        red[wave][1] = (float)wmax;
        red[wave][2] = fvals[0];
        red[wave][3] = fvals[1];
        red[wave][4] = fvals[2];
        red[wave][5] = fvals[3];
        red[wave][6] = fvals[4];
        red[wave][7] = (float)wles;
    }
    __syncthreads();
    if (tid < NACC) {
        float t = 0.f;
        #pragma unroll
        for (int w = 0; w < NWAVES; ++w) t += red[w][tid];
        const int slot = b * SLOTS_PER_B + hwblk * DSEGS + seg;
        ws[(size_t)slot * NACC + tid] = t;   // distinct slot: no memset, no atomics
    }
}

__global__ __launch_bounds__(1024)
void finalize_kernel(const float* __restrict__ ws, float* __restrict__ out)
{
    const int tid = (int)threadIdx.x;
    const int b   = tid >> 6;      // batch 0..15 (one 64-lane wave per batch)
    const int k   = tid & 63;      // slot within batch (64 slots)

    double a[NACC];
    const float* p = ws + ((size_t)(b * SLOTS_PER_B + k)) * NACC;
    #pragma unroll
    for (int vi = 0; vi < NACC; ++vi) a[vi] = (double)p[vi];

    #pragma unroll
    for (int vi = 0; vi < NACC; ++vi) {
        #pragma unroll
        for (int off = 32; off > 0; off >>= 1)
            a[vi] += __shfl_down(a[vi], off, 64);
    }

    __shared__ double bl[NB];
    if (k == 0) {
        const double cnt    = a[0];
        const double cntmax = a[1];
        const double sd     = a[2];
        const double sh     = a[3];
        const double sw     = a[4];
        const double sm     = a[5];
        const double sm2    = a[6];
        const double les    = a[7];

        const double inv_vox = 1.0 / (double)VOX;
        const double act  = cnt    * inv_vox;
        const double high = cntmax * inv_vox;

        double loss = fmax(0.005 - act, 0.0) * 15.0      // W_MIN
                    + fmax(high - 0.03, 0.0) * 5.0;      // W_MAX

        const double grad_den = 127.0 * 128.0 * 128.0;   // diff-array size
        const double avg_grad = (sd + sh + sw) / (3.0 * grad_den);
        if (les > 0.5)
            loss += fmin(avg_grad, 1.0) * 5.0;           // W_CONT

        const double cnt_safe = fmax(cnt, 1.0);
        const double m  = sm / cnt_safe;
        double sq = sm2 - 2.0 * m * sm + m * m * cnt;
        if (sq < 0.0) sq = 0.0;

        const bool gate = (act > 0.001) && (cnt > 1.0);
        if (gate) {
            const double var     = sq / fmax(cnt - 1.0, 1.0);
            const double rel_std = sqrt(var) / (m + 1e-6);
            loss += exp(-5.0 * rel_std) * 7.0;           // W_SIZE
        }
        bl[b] = loss;
    }
    __syncthreads();
    if (tid == 0) {
        double s = 0.0;
        #pragma unroll
        for (int i = 0; i < NB; ++i) s += bl[i];
        out[0] = (float)(s / (double)NB);
    }
}

extern "C" void kernel_launch(void* const* d_in, const int* in_sizes, int n_in,
                              void* d_out, int out_size, void* d_ws, size_t ws_size,
                              hipStream_t stream)
{
    const float* pred = (const float*)d_in[0];
    float* out        = (float*)d_out;
    float* ws         = (float*)d_ws;

    dim3 grid(DSEGS, HWBLKS, NB);
    partial_kernel<<<grid, THREADS, 0, stream>>>(pred, ws);
    finalize_kernel<<<1, 1024, 0, stream>>>(ws, out);
}

// Round 4
// 190.622 us; speedup vs baseline: 1.0181x; 1.0181x over previous
//
#include <hip/hip_runtime.h>
#include <math.h>

#define MIN_T    0.01f
#define MAX_T    0.5f
#define LESION_T 0.3f

constexpr int NB       = 16;
constexpr int DIM      = 128;
constexpr int PLANE_F4 = DIM * DIM / 4;        // 4096 float4 per plane
constexpr int VOX      = DIM * DIM * DIM;      // 2,097,152
constexpr int THREADS  = 512;                  // 16 rows x 32 float4-cols
constexpr int ROWS     = 16;                   // rows of a plane per block
constexpr int HWBLKS   = DIM / ROWS;           // 8 row-slabs
constexpr int DSEGS    = 4;                    // d-axis segments
constexpr int DPS      = DIM / DSEGS;          // 32 planes per segment
constexpr int NACC     = 8;
constexpr int SLOTS_PER_B = DSEGS * HWBLKS;    // 32 partial slots per batch
constexpr int NWAVES   = THREADS / 64;         // 8

// Per-slot accumulator layout (floats):
// 0: cnt(>MIN_T)  1: cnt(>MAX_T)  2: sum|d-diff|  3: sum|h-diff|
// 4: sum|w-diff|  5: sum s*mask   6: sum s^2*mask 7: cnt(>LESION_T)
//
// Structure notes (evidence, rounds 0-3):
//  - dual-load of row h+1 (vh) is an L1 hit for 15/16 rows; LDS plane-exchange
//    with per-plane barriers measured ~3-4us SLOWER (R1). Keep dual-load.
//  - forced 8 waves/SIMD via launch_bounds(512,8)+ballot REGRESSED (R3);
//    16 waves/CU is sufficient occupancy. Keep plain cndmask counting.
//  - direct per-slot stores: no memset dispatch, no atomics. (absmax 0)
//  - R4: 2-plane-deep software pipeline — issue plane d+1 loads while
//    processing plane d-1; covers queuing-inflated HBM latency (~2x issue
//    distance, 64KB/CU in flight).
__global__ __launch_bounds__(THREADS)
void partial_kernel(const float* __restrict__ pred, float* __restrict__ ws)
{
    const int seg   = blockIdx.x;
    const int hwblk = blockIdx.y;
    const int b     = blockIdx.z;
    const int tid   = (int)threadIdx.x;
    const int r     = tid >> 5;                // local row 0..15

    const int  h    = hwblk * ROWS + r;
    const bool do_h = (h < DIM - 1);           // h-pair (h,h+1) exists
    const bool do_w = ((tid & 31) != 31);      // w-cross pair exists

    const float4* __restrict__ s4 =
        reinterpret_cast<const float4*>(pred + (size_t)b * VOX);

    const int d0    = seg * DPS;
    const int d_end = (seg == DSEGS - 1) ? (DIM - 1) : (d0 + DPS);

    float cnt_min = 0.f, cnt_max = 0.f, sum_d = 0.f, sum_h = 0.f,
          sum_w = 0.f, sm = 0.f, sm2 = 0.f, les = 0.f;
    const float4 zero4 = { 0.f, 0.f, 0.f, 0.f };

    // element stats + w/h diffs for one float4 (its plane)
    auto process = [&](const float4& v, const float4& vh) {
        const float xs[4] = { v.x, v.y, v.z, v.w };
        #pragma unroll
        for (int j = 0; j < 4; ++j) {
            const float x  = xs[j];
            const float mk = (x > MIN_T) ? 1.0f : 0.0f;
            cnt_min += mk;
            cnt_max += (x > MAX_T)    ? 1.0f : 0.0f;
            les     += (x > LESION_T) ? 1.0f : 0.0f;
            sm      += x * mk;
            sm2     += x * x * mk;
        }
        sum_w += fabsf(v.y - v.x) + fabsf(v.z - v.y) + fabsf(v.w - v.z);
        const float nx = __shfl_down(v.x, 1, 64);   // next float4's .x (same row)
        if (do_w) sum_w += fabsf(nx - v.w);
        if (do_h) sum_h += fabsf(vh.x - v.x) + fabsf(vh.y - v.y)
                         + fabsf(vh.z - v.z) + fabsf(vh.w - v.w);
    };

    // thread owns float4 at (h, w4 = tid&31) on every plane.
    // Pipeline: A = plane d-1, B = plane d, C = prefetch of plane d+1.
    size_t base = (size_t)d0 * PLANE_F4 + hwblk * THREADS + tid;

    float4 vA  = s4[base];
    float4 vAh = do_h ? s4[base + 32] : zero4;
    float4 vB  = s4[base + PLANE_F4];
    float4 vBh = do_h ? s4[base + PLANE_F4 + 32] : zero4;

    // pairs (d-1, d) for d in [d0+1, d_end]; stats for planes d0 .. d_end-1
    #pragma unroll 2
    for (int d = d0 + 1; d <= d_end; ++d) {
        float4 vC = zero4, vCh = zero4;
        if (d < d_end) {                        // uniform branch; no OOB, no waste
            vC  = s4[base + 2 * (size_t)PLANE_F4];
            vCh = do_h ? s4[base + 2 * (size_t)PLANE_F4 + 32] : zero4;
        }
        process(vA, vAh);
        sum_d += fabsf(vB.x - vA.x) + fabsf(vB.y - vA.y)
               + fabsf(vB.z - vA.z) + fabsf(vB.w - vA.w);
        vA = vB; vAh = vBh;
        vB = vC; vBh = vCh;
        base += PLANE_F4;
    }
    if (seg == DSEGS - 1)       // plane 127's element stats (not a d-pair source)
        process(vA, vAh);

    // wave (64-lane) shuffle reduction, then LDS across 8 waves
    float vals[NACC] = { cnt_min, cnt_max, sum_d, sum_h, sum_w, sm, sm2, les };
    #pragma unroll
    for (int vi = 0; vi < NACC; ++vi) {
        float x = vals[vi];
        #pragma unroll
        for (int off = 32; off > 0; off >>= 1)
            x += __shfl_down(x, off, 64);
        vals[vi] = x;
    }

    __shared__ float red[NWAVES][NACC];
    const int wave = tid >> 6;
    const int lane = tid & 63;
    if (lane == 0) {
        #pragma unroll
        for (int vi = 0; vi < NACC; ++vi) red[wave][vi] = vals[vi];
    }
    __syncthreads();
    if (tid < NACC) {
        float t = 0.f;
        #pragma unroll
        for (int w = 0; w < NWAVES; ++w) t += red[w][tid];
        const int slot = b * SLOTS_PER_B + hwblk * DSEGS + seg;
        ws[(size_t)slot * NACC + tid] = t;   // distinct slot: no memset, no atomics
    }
}

__global__ __launch_bounds__(512)
void finalize_kernel(const float* __restrict__ ws, float* __restrict__ out)
{
    const int tid = (int)threadIdx.x;
    const int b   = tid >> 5;      // batch 0..15 (one 32-lane group per batch)
    const int k   = tid & 31;      // slot within batch

    double a[NACC];
    const float* p = ws + ((size_t)(b * SLOTS_PER_B + k)) * NACC;
    #pragma unroll
    for (int vi = 0; vi < NACC; ++vi) a[vi] = (double)p[vi];

    #pragma unroll
    for (int vi = 0; vi < NACC; ++vi) {
        #pragma unroll
        for (int off = 16; off > 0; off >>= 1)
            a[vi] += __shfl_down(a[vi], off, 32);
    }

    __shared__ double bl[NB];
    if (k == 0) {
        const double cnt    = a[0];
        const double cntmax = a[1];
        const double sd     = a[2];
        const double sh     = a[3];
        const double sw     = a[4];
        const double sm     = a[5];
        const double sm2    = a[6];
        const double les    = a[7];

        const double inv_vox = 1.0 / (double)VOX;
        const double act  = cnt    * inv_vox;
        const double high = cntmax * inv_vox;

        double loss = fmax(0.005 - act, 0.0) * 15.0      // W_MIN
                    + fmax(high - 0.03, 0.0) * 5.0;      // W_MAX

        const double grad_den = 127.0 * 128.0 * 128.0;   // diff-array size
        const double avg_grad = (sd + sh + sw) / (3.0 * grad_den);
        if (les > 0.5)
            loss += fmin(avg_grad, 1.0) * 5.0;           // W_CONT

        const double cnt_safe = fmax(cnt, 1.0);
        const double m  = sm / cnt_safe;
        double sq = sm2 - 2.0 * m * sm + m * m * cnt;
        if (sq < 0.0) sq = 0.0;

        const bool gate = (act > 0.001) && (cnt > 1.0);
        if (gate) {
            const double var     = sq / fmax(cnt - 1.0, 1.0);
            const double rel_std = sqrt(var) / (m + 1e-6);
            loss += exp(-5.0 * rel_std) * 7.0;           // W_SIZE
        }
        bl[b] = loss;
    }
    __syncthreads();
    if (tid == 0) {
        double s = 0.0;
        #pragma unroll
        for (int i = 0; i < NB; ++i) s += bl[i];
        out[0] = (float)(s / (double)NB);
    }
}

extern "C" void kernel_launch(void* const* d_in, const int* in_sizes, int n_in,
                              void* d_out, int out_size, void* d_ws, size_t ws_size,
                              hipStream_t stream)
{
    const float* pred = (const float*)d_in[0];
    float* out        = (float*)d_out;
    float* ws         = (float*)d_ws;

    dim3 grid(DSEGS, HWBLKS, NB);
    partial_kernel<<<grid, THREADS, 0, stream>>>(pred, ws);
    finalize_kernel<<<1, 512, 0, stream>>>(ws, out);
}